// Round 6
// baseline (13.159 us; speedup 1.0000x reference)
//
#include <hip/hip_runtime.h>
#include <float.h>

// Problem constants (from reference)
#define NB 5                    // N_BANDS
#define BB 256                  // B
#define LL 800                  // L
#define TT (NB * LL)            // 4000 values per batch row
#define NN (TT - NB)            // 3995 output diffs per row

constexpr int THR  = 512;          // 8 waves per block
constexpr int NBUK = 4096;         // lambda ~= 0.98
constexpr int BPT  = NBUK / THR;   // 8 buckets per thread in the scan
constexpr int NV4  = TT / 4;       // 1000 float4 loads cover the row exactly
constexpr int EPT  = 8;            // elements per thread (2 x float4)

__global__ __launch_bounds__(THR, 4)
void bucket_rank_diff3(const float* __restrict__ in,
                       const int* __restrict__ ntotal,
                       float* __restrict__ out)
{
    __shared__ float scat[TT];          // bucket-grouped values
    __shared__ float srt[TT];           // fully sorted
    __shared__ int   cnt[NBUK];         // histogram (atomic returns in-bucket offset)
    __shared__ int   bstart[NBUK + 1];  // bucket begin; bstart[NBUK] = TT
    __shared__ int   wsum[8];           // per-wave scan totals

    const int b    = blockIdx.x;
    const int tid  = threadIdx.x;
    const int lane = tid & 63;
    const int wid  = tid >> 6;
    const float scale = (float)NBUK / 1000.0f;  // monotone bucket map, vals in [0,1000)

    // init histogram (8 ints per thread, 32B-aligned -> 2 x b128 writes)
    #pragma unroll
    for (int k = 0; k < BPT; k += 4)
        *reinterpret_cast<int4*>(&cnt[tid * BPT + k]) = make_int4(0, 0, 0, 0);
    __syncthreads();

    // ---- Phase 1: two float4 loads per thread; histogram atomic returns
    //      the within-bucket arrival offset (deterministic scatter slot).
    float v[EPT];
    int   g[EPT];
    int   off[EPT];
    #pragma unroll
    for (int t = 0; t < 2; ++t) {
        int f = tid + t * THR;              // float4 index in [0, 1024)
        if (f < NV4) {
            int band = f / 200;             // 200 float4 per (band,row) chunk
            int l4   = f - band * 200;
            float4 x4 = *(reinterpret_cast<const float4*>(in + (band * BB + b) * LL) + l4);
            float xs[4] = {x4.x, x4.y, x4.z, x4.w};
            #pragma unroll
            for (int k = 0; k < 4; ++k) {
                int e  = t * 4 + k;
                float x = xs[k];
                int gg = (int)(x * scale);
                gg = gg < 0 ? 0 : (gg > NBUK - 1 ? NBUK - 1 : gg);
                v[e] = x; g[e] = gg;
                off[e] = atomicAdd(&cnt[gg], 1);
            }
        } else {
            #pragma unroll
            for (int k = 0; k < 4; ++k) g[t * 4 + k] = -1;
        }
    }
    __syncthreads();

    // ---- Phase 2: exclusive prefix sum over 4096 bucket counts.
    int c[BPT];
    int s = 0;
    #pragma unroll
    for (int k = 0; k < BPT; k += 4) {
        int4 q = *reinterpret_cast<int4*>(&cnt[BPT * tid + k]);
        c[k] = q.x; c[k + 1] = q.y; c[k + 2] = q.z; c[k + 3] = q.w;
    }
    #pragma unroll
    for (int k = 0; k < BPT; ++k) s += c[k];
    int inc = s;                       // inclusive within-wave scan of thread sums
    #pragma unroll
    for (int d = 1; d < 64; d <<= 1) {
        int t = __shfl_up(inc, d);
        if (lane >= d) inc += t;
    }
    if (lane == 63) wsum[wid] = inc;
    __syncthreads();
    int wo = 0;                        // per-thread wave offset (LDS broadcast reads)
    #pragma unroll
    for (int w = 0; w < 8; ++w) wo += (w < wid) ? wsum[w] : 0;
    int run = (inc - s) + wo;
    #pragma unroll
    for (int k = 0; k < BPT; ++k) { bstart[BPT * tid + k] = run; run += c[k]; }
    if (tid == 0) bstart[NBUK] = TT;
    __syncthreads();

    // ---- Phase 3: deterministic scatter — position = bstart[g] + off.
    #pragma unroll
    for (int e = 0; e < EPT; ++e)
        if (g[e] >= 0) scat[bstart[g[e]] + off[e]] = v[e];
    __syncthreads();

    // ---- Phase 4: rank-count, redistributed BY POSITION over scat[] so all
    //      512 threads get equal work; tie-break by scat index (unique).
    #pragma unroll
    for (int t = 0; t < EPT; ++t) {
        int i = tid + t * THR;             // 0..4095
        if (i < TT) {
            float x  = scat[i];
            int   gg = (int)(x * scale);
            gg = gg < 0 ? 0 : (gg > NBUK - 1 ? NBUK - 1 : gg);
            int lo = bstart[gg];
            int hi = bstart[gg + 1];
            int r  = lo;
            for (int j = lo; j < hi; ++j) {
                float w = scat[j];
                if (w < x || (w == x && j < i)) ++r;
            }
            srt[r] = x;
        }
    }
    __syncthreads();

    // ---- Phase 5: adjacent diffs of sorted[4:], masked, coalesced store.
    const int nt = ntotal[b];
    #pragma unroll
    for (int t = 0; t < EPT; ++t) {
        int i = tid + t * THR;
        if (i < NN) {
            float d = srt[i + NB] - srt[i + NB - 1];
            out[b * NN + i] = (i < nt) ? d : 0.0f;
        }
    }
}

extern "C" void kernel_launch(void* const* d_in, const int* in_sizes, int n_in,
                              void* d_out, int out_size, void* d_ws, size_t ws_size,
                              hipStream_t stream) {
    const float* in  = (const float*)d_in[0];   // (5, 256, 800) fp32
    const int*   nt  = (const int*)d_in[1];     // (256,) int32
    float*       out = (float*)d_out;           // (256, 3995) fp32
    (void)in_sizes; (void)n_in; (void)out_size; (void)d_ws; (void)ws_size;
    bucket_rank_diff3<<<BB, THR, 0, stream>>>(in, nt, out);
}